// Round 7
// baseline (3411.185 us; speedup 1.0000x reference)
//
#include <hip/hip_runtime.h>

// n must be <= 256*1024 (bucket = dst >> 8, B <= 1024).

typedef unsigned long long u64;

// ---------------- CSR build: tp (small, 200K edges) — old path ----------------

__global__ __launch_bounds__(256) void hist_tp_kernel(
    const int* __restrict__ ei_tp, int E_tp, int* __restrict__ deg_tp)
{
    int i = blockIdx.x * 256 + threadIdx.x;
    if (i < E_tp) atomicAdd(&deg_tp[ei_tp[E_tp + i]], 1);
}

__global__ __launch_bounds__(256) void alloc_tp_kernel(
    int n, const int* __restrict__ deg_tp,
    int* __restrict__ row_tp, int* __restrict__ next_tp, int* __restrict__ ctr)
{
    int i = blockIdx.x * 256 + threadIdx.x;
    if (i >= n) return;
    int d = deg_tp[i];
    int r = atomicAdd(&ctr[0], d);
    row_tp[i] = r; next_tp[i] = r;
}

__global__ __launch_bounds__(256) void fill_tp_kernel(
    const int* __restrict__ ei_tp, int E_tp,
    int* __restrict__ next_tp, int* __restrict__ col_tp)
{
    int i = blockIdx.x * 256 + threadIdx.x;
    if (i >= E_tp) return;
    int src = ei_tp[i];
    int dst = ei_tp[E_tp + i];
    col_tp[atomicAdd(&next_tp[dst], 1)] = src;
}

// ---------------- CSR build: it (3.2M edges) — multisplit, 256-node buckets ----

__global__ __launch_bounds__(256) void bucket_count_kernel(
    const int* __restrict__ ei_it, int E_it, int B, int* __restrict__ bcnt)
{
    __shared__ int h[1024];
    for (int j = threadIdx.x; j < 1024; j += 256) h[j] = 0;
    __syncthreads();
    const int stride = gridDim.x * 256;
    for (int i = blockIdx.x * 256 + threadIdx.x; i < E_it; i += stride)
        atomicAdd(&h[ei_it[E_it + i] >> 8], 1);
    __syncthreads();
    for (int j = threadIdx.x; j < B; j += 256) {
        int v = h[j];
        if (v) atomicAdd(&bcnt[j], v);
    }
}

__global__ __launch_bounds__(256) void bucket_prefix_kernel(
    int B, const int* __restrict__ bcnt, int* __restrict__ bbase, int* __restrict__ bcursor)
{
    __shared__ int lpart[256];
    const int t = threadIdx.x;
    const int i4 = 4 * t;
    int l0 = (i4     < B) ? bcnt[i4]     : 0;
    int l1 = (i4 + 1 < B) ? bcnt[i4 + 1] : 0;
    int l2 = (i4 + 2 < B) ? bcnt[i4 + 2] : 0;
    int l3 = (i4 + 3 < B) ? bcnt[i4 + 3] : 0;
    const int lsum = l0 + l1 + l2 + l3;
    lpart[t] = lsum;
    __syncthreads();
    for (int off = 1; off < 256; off <<= 1) {
        int v = (t >= off) ? lpart[t - off] : 0;
        __syncthreads();
        if (t >= off) lpart[t] += v;
        __syncthreads();
    }
    const int ex = lpart[t] - lsum;
    if (t == 0) bbase[0] = 0;
    const int p[4] = {ex, ex + l0, ex + l0 + l1, ex + l0 + l1 + l2};
    const int l[4] = {l0, l1, l2, l3};
#pragma unroll
    for (int k = 0; k < 4; k++) {
        int i = i4 + k;
        if (i < B) {
            bbase[i + 1] = p[k] + l[k];
            bcursor[i]   = p[k];
        }
    }
}

__global__ __launch_bounds__(256) void multisplit_kernel(
    const int* __restrict__ ei_it, int E_it,
    int* __restrict__ bcursor, u64* __restrict__ ebuf)
{
    __shared__ int cnt[1024];
    __shared__ int gbase[1024];
    const int tid  = threadIdx.x;
    const int base = blockIdx.x * 2048;
    for (int j = tid; j < 1024; j += 256) cnt[j] = 0;
    __syncthreads();

    int src[8], dst[8], rk[8], bk[8];
#pragma unroll
    for (int k = 0; k < 8; k++) {
        int i = base + k * 256 + tid;
        if (i < E_it) {
            src[k] = ei_it[i];
            dst[k] = ei_it[E_it + i];
            bk[k]  = dst[k] >> 8;
            rk[k]  = atomicAdd(&cnt[bk[k]], 1);
        } else rk[k] = -1;
    }
    __syncthreads();
    for (int j = tid; j < 1024; j += 256) {
        int c = cnt[j];
        if (c) gbase[j] = atomicAdd(&bcursor[j], c);
    }
    __syncthreads();
#pragma unroll
    for (int k = 0; k < 8; k++) {
        if (rk[k] >= 0) {
            int pos = gbase[bk[k]] + rk[k];
            ebuf[pos] = ((u64)(unsigned)dst[k] << 32) | (unsigned)src[k];
        }
    }
}

// One block per 256-node bucket: deg/row/inv_cnt + col scatter (col_it used by agg6).
__global__ __launch_bounds__(256) void csr_it_kernel(
    int n, const u64* __restrict__ ebuf, const int* __restrict__ bbase,
    int* __restrict__ row_it, int* __restrict__ deg_it,
    float* __restrict__ inv_cnt, int* __restrict__ col_it)
{
    __shared__ int lnext[256];
    __shared__ int s[256];
    __shared__ int ldeg[256];
    const int b = blockIdx.x;
    const int t = threadIdx.x;
    const int node_lo = b << 8;
    const int nn = min(256, n - node_lo);
    const int e0 = bbase[b], e1 = bbase[b + 1];

    ldeg[t] = 0;
    __syncthreads();
    for (int i = e0 + t; i < e1; i += 256)
        atomicAdd(&ldeg[(int)(ebuf[i] >> 32) - node_lo], 1);
    __syncthreads();

    const int v = (t < nn) ? ldeg[t] : 0;
    s[t] = v;
    __syncthreads();
    for (int off = 1; off < 256; off <<= 1) {
        int w = (t >= off) ? s[t - off] : 0;
        __syncthreads();
        if (t >= off) s[t] += w;
        __syncthreads();
    }
    const int ex = s[t] - v;
    if (t < nn) {
        lnext[t] = ex;
        row_it[node_lo + t]  = e0 + ex;
        deg_it[node_lo + t]  = v;
        inv_cnt[node_lo + t] = 1.0f / (float)max(v, 1);
    }
    __syncthreads();
    for (int i = e0 + t; i < e1; i += 256) {
        u64 val = ebuf[i];
        int dl  = (int)(val >> 32) - node_lo;
        int pos = atomicAdd(&lnext[dl], 1);
        col_it[e0 + pos] = (int)(val & 0xffffffffu);
    }
}

// ---------------- Weight prep ----------------

__global__ __launch_bounds__(256) void prep_weights_kernel(
    const float* __restrict__ W0_rel, const float* __restrict__ W0_root,
    const float* __restrict__ b0, const float* __restrict__ W_rel,
    const float* __restrict__ W_root, const float* __restrict__ b,
    float* __restrict__ wcat)
{
    int i = blockIdx.x * 256 + threadIdx.x;
    if (i < 576) {
        int k = i >> 5, j = i & 31;
        float v;
        if (k < 6)       v = W0_rel[k * 32 + j];
        else if (k < 12) v = W0_rel[192 + (k - 6) * 32 + j];
        else             v = W0_root[(k - 12) * 32 + j] + W0_root[192 + (k - 12) * 32 + j];
        wcat[i] = v;
    } else if (i < 576 + 4 * 3072) {
        int t = i - 576;
        int l = t / 3072, r = t % 3072;
        int k = r >> 5, j = r & 31;
        const float* Wr = W_rel  + l * 2048;
        const float* Wt = W_root + l * 2048;
        float v;
        if (k < 32)      v = Wr[k * 32 + j];
        else if (k < 64) v = Wr[1024 + (k - 32) * 32 + j];
        else             v = Wt[(k - 64) * 32 + j] + Wt[1024 + (k - 64) * 32 + j];
        wcat[i] = v;
    } else if (i < 13024) {
        int t = i - 12864;
        if (t < 32) wcat[i] = b0[t] + b0[32 + t];
        else {
            int l = (t - 32) >> 5, j = (t - 32) & 31;
            wcat[i] = b[l * 64 + j] + b[l * 64 + 32 + j];
        }
    }
}

// ---------------- Aggregation (C=32): edge-parallel LDS accumulate ----------------
// One block per 256-node bucket. acc[256][33] in LDS (pad 33 spreads banks by
// dst). Edge loop: 32 groups x 8 lanes, each group one edge: coalesced 128 B
// row gather + 4 ds_add_f32/lane. Unroll 4 -> 128 independent gathers in
// flight per block. Epilogue: tp gather (deg~1) + mean scale + agg write.

__global__ __launch_bounds__(256) void agg32_lds_kernel(
    int n, const float* __restrict__ hin,
    const u64* __restrict__ ebuf, const int* __restrict__ bbase,
    const int* __restrict__ row_tp, const int* __restrict__ deg_tp,
    const int* __restrict__ col_tp,
    const float* __restrict__ inv_cnt, float* __restrict__ agg)
{
    __shared__ float acc[256 * 33];
    const int tid = threadIdx.x;
    const int b = blockIdx.x;
    const int node_lo = b << 8;
    const int nn = min(256, n - node_lo);
    const int e0 = bbase[b], e1 = bbase[b + 1];
    const int gid = tid >> 3;          // 0..31
    const int q   = tid & 7;           // channel quad

    for (int i = tid; i < 256 * 33; i += 256) acc[i] = 0.f;
    __syncthreads();

    int i = e0 + gid;
    for (; i + 96 < e1; i += 128) {
        const u64 v0 = ebuf[i];
        const u64 v1 = ebuf[i + 32];
        const u64 v2 = ebuf[i + 64];
        const u64 v3 = ebuf[i + 96];
        const float4 r0 = *(const float4*)&hin[(size_t)(unsigned)(v0 & 0xffffffffu) * 32 + q * 4];
        const float4 r1 = *(const float4*)&hin[(size_t)(unsigned)(v1 & 0xffffffffu) * 32 + q * 4];
        const float4 r2 = *(const float4*)&hin[(size_t)(unsigned)(v2 & 0xffffffffu) * 32 + q * 4];
        const float4 r3 = *(const float4*)&hin[(size_t)(unsigned)(v3 & 0xffffffffu) * 32 + q * 4];
        float* a0 = &acc[((int)(v0 >> 32) - node_lo) * 33 + q * 4];
        float* a1 = &acc[((int)(v1 >> 32) - node_lo) * 33 + q * 4];
        float* a2 = &acc[((int)(v2 >> 32) - node_lo) * 33 + q * 4];
        float* a3 = &acc[((int)(v3 >> 32) - node_lo) * 33 + q * 4];
        atomicAdd(a0 + 0, r0.x); atomicAdd(a0 + 1, r0.y); atomicAdd(a0 + 2, r0.z); atomicAdd(a0 + 3, r0.w);
        atomicAdd(a1 + 0, r1.x); atomicAdd(a1 + 1, r1.y); atomicAdd(a1 + 2, r1.z); atomicAdd(a1 + 3, r1.w);
        atomicAdd(a2 + 0, r2.x); atomicAdd(a2 + 1, r2.y); atomicAdd(a2 + 2, r2.z); atomicAdd(a2 + 3, r2.w);
        atomicAdd(a3 + 0, r3.x); atomicAdd(a3 + 1, r3.y); atomicAdd(a3 + 2, r3.z); atomicAdd(a3 + 3, r3.w);
    }
    for (; i < e1; i += 32) {
        const u64 v = ebuf[i];
        const float4 r = *(const float4*)&hin[(size_t)(unsigned)(v & 0xffffffffu) * 32 + q * 4];
        float* a = &acc[((int)(v >> 32) - node_lo) * 33 + q * 4];
        atomicAdd(a + 0, r.x); atomicAdd(a + 1, r.y); atomicAdd(a + 2, r.z); atomicAdd(a + 3, r.w);
    }
    __syncthreads();

    for (int nl = gid; nl < nn; nl += 32) {
        const int node = node_lo + nl;
        const float ic = inv_cnt[node];
        const float* a = &acc[nl * 33 + q * 4];
        float4 aM = make_float4(a[0] * ic, a[1] * ic, a[2] * ic, a[3] * ic);

        float4 aA = make_float4(0.f, 0.f, 0.f, 0.f);
        const int rs = row_tp[node], d = deg_tp[node];
        for (int e = 0; e < d; e++) {
            const int j = col_tp[rs + e];
            const float4 v = *(const float4*)&hin[(size_t)j * 32 + q * 4];
            aA.x += v.x; aA.y += v.y; aA.z += v.z; aA.w += v.w;
        }
        *(float4*)&agg[(size_t)node * 64 + q * 4]      = aA;
        *(float4*)&agg[(size_t)node * 64 + 32 + q * 4] = aM;
    }
}

// ---------------- Aggregation (C=6, head): 8 nodes per wave ----------------

__global__ __launch_bounds__(256, 8) void agg6_kernel(
    int n, const float* __restrict__ hin,
    const int* __restrict__ row_it, const int* __restrict__ deg_it, const int* __restrict__ col_it,
    const int* __restrict__ row_tp, const int* __restrict__ deg_tp, const int* __restrict__ col_tp,
    const float* __restrict__ inv_cnt, float* __restrict__ agg)
{
    const int wave = threadIdx.x >> 6;
    const int lane = threadIdx.x & 63;
    const int g = lane >> 3;
    const int c = lane & 7;
    const int cc = (c < 6) ? c : 0;
    const int node = (blockIdx.x * 4 + wave) * 8 + g;
    if (node >= n) return;

    float aA = 0.f, aM = 0.f;
    {
        const int rs = row_tp[node], d = deg_tp[node];
        for (int e = 0; e < d; e++) {
            const int j = col_tp[rs + e];
            aA += hin[(size_t)j * 6 + cc];
        }
    }
    {
        const int rs = row_it[node], d = deg_it[node];
        int e = 0;
        for (; e + 3 < d; e += 4) {
            const int j0 = col_it[rs + e];
            const int j1 = col_it[rs + e + 1];
            const int j2 = col_it[rs + e + 2];
            const int j3 = col_it[rs + e + 3];
            aM += (hin[(size_t)j0 * 6 + cc] + hin[(size_t)j1 * 6 + cc])
                + (hin[(size_t)j2 * 6 + cc] + hin[(size_t)j3 * 6 + cc]);
        }
        for (; e < d; e++) {
            const int j = col_it[rs + e];
            aM += hin[(size_t)j * 6 + cc];
        }
    }

    if (c < 6) {
        agg[(size_t)node * 12 + c]     = aA;
        agg[(size_t)node * 12 + 6 + c] = aM * inv_cnt[node];
    }
}

// ---------------- Per-layer GEMM, register version ----------------

template <int CI, bool RESID>
__global__ __launch_bounds__(256) void gemm_reg_kernel(
    int n, const float* __restrict__ agg, const float* __restrict__ hin,
    const float* __restrict__ Wcat, const float* __restrict__ bias,
    float* __restrict__ hout)
{
    const int node = blockIdx.x * 256 + threadIdx.x;
    if (node >= n) return;

    float acc[32];
#pragma unroll
    for (int j = 0; j < 32; j++) acc[j] = bias[j];

    if constexpr (CI == 32) {
        const float* arow = agg + (size_t)node * 64;
#pragma unroll
        for (int c = 0; c < 8; c++) {
            const float4 a0 = *(const float4*)(arow + c * 8);
            const float4 a1 = *(const float4*)(arow + c * 8 + 4);
            const float av[8] = {a0.x, a0.y, a0.z, a0.w, a1.x, a1.y, a1.z, a1.w};
#pragma unroll
            for (int kk = 0; kk < 8; kk++) {
                const float* wr = Wcat + (c * 8 + kk) * 32;
#pragma unroll
                for (int j = 0; j < 32; j++) acc[j] = fmaf(av[kk], wr[j], acc[j]);
            }
        }
        const float* hrow = hin + (size_t)node * 32;
#pragma unroll
        for (int c = 0; c < 4; c++) {
            const float4 a0 = *(const float4*)(hrow + c * 8);
            const float4 a1 = *(const float4*)(hrow + c * 8 + 4);
            const float av[8] = {a0.x, a0.y, a0.z, a0.w, a1.x, a1.y, a1.z, a1.w};
#pragma unroll
            for (int kk = 0; kk < 8; kk++) {
                const float* wr = Wcat + (64 + c * 8 + kk) * 32;
#pragma unroll
                for (int j = 0; j < 32; j++) acc[j] = fmaf(av[kk], wr[j], acc[j]);
            }
            if (RESID) {
#pragma unroll
                for (int kk = 0; kk < 8; kk++) acc[c * 8 + kk] += av[kk];
            }
        }
    } else {  // CI == 6, K = 18
        const float* arow = agg + (size_t)node * 12;
#pragma unroll
        for (int k = 0; k < 12; k++) {
            const float a = arow[k];
            const float* wr = Wcat + k * 32;
#pragma unroll
            for (int j = 0; j < 32; j++) acc[j] = fmaf(a, wr[j], acc[j]);
        }
        const float* xrow = hin + (size_t)node * 6;
#pragma unroll
        for (int k = 0; k < 6; k++) {
            const float a = xrow[k];
            const float* wr = Wcat + (12 + k) * 32;
#pragma unroll
            for (int j = 0; j < 32; j++) acc[j] = fmaf(a, wr[j], acc[j]);
        }
    }

#pragma unroll
    for (int j = 0; j < 32; j++) acc[j] = fmaxf(acc[j], 0.f);
    float* orow = hout + (size_t)node * 32;
#pragma unroll
    for (int j = 0; j < 32; j += 4)
        *(float4*)(orow + j) = make_float4(acc[j], acc[j + 1], acc[j + 2], acc[j + 3]);
}

// ---------------- Final linear: out = h @ Wout + bout ----------------
// v4: lane = column (coalesced W loads and stores). 8 nodes x 128 cols per
// 256-thread block; h staged in LDS, read via same-address broadcast.

__global__ __launch_bounds__(256) void final_kernel(
    int n, const float* __restrict__ h, const float* __restrict__ Wout,
    const float* __restrict__ bout, float* __restrict__ out)
{
    __shared__ float sH[8 * 33];
    const int tid = threadIdx.x;
    const int nrow = tid >> 5;        // 0..7
    const int cg = tid & 31;
    const int col4 = cg * 4;
    const int n0 = blockIdx.x * 8;

    {   // stage 8 node rows (coalesced: 32 lanes cover one 128 B row)
        const int node = n0 + nrow;
        sH[nrow * 33 + cg] = (node < n) ? h[(size_t)node * 32 + cg] : 0.f;
    }
    __syncthreads();

    float acc[4];
    {
        const float4 bv = *(const float4*)&bout[col4];
        acc[0] = bv.x; acc[1] = bv.y; acc[2] = bv.z; acc[3] = bv.w;
    }

#pragma unroll
    for (int k = 0; k < 32; k++) {
        const float a = sH[nrow * 33 + k];                    // LDS broadcast
        const float4 w = *(const float4*)&Wout[k * 128 + col4]; // coalesced, L1
        acc[0] = fmaf(a, w.x, acc[0]);
        acc[1] = fmaf(a, w.y, acc[1]);
        acc[2] = fmaf(a, w.z, acc[2]);
        acc[3] = fmaf(a, w.w, acc[3]);
    }

    const int node = n0 + nrow;
    if (node < n)
        *(float4*)&out[(size_t)node * 128 + col4] =
            make_float4(acc[0], acc[1], acc[2], acc[3]);
}

// ---------------- launch ----------------

extern "C" void kernel_launch(void* const* d_in, const int* in_sizes, int n_in,
                              void* d_out, int out_size, void* d_ws, size_t ws_size,
                              hipStream_t stream)
{
    const float* x      = (const float*)d_in[0];
    const int*   ei_tp  = (const int*)d_in[1];
    const int*   ei_it  = (const int*)d_in[2];
    const float* W0_rel  = (const float*)d_in[3];
    const float* W0_root = (const float*)d_in[4];
    const float* b0      = (const float*)d_in[5];
    const float* W_rel   = (const float*)d_in[6];
    const float* W_root  = (const float*)d_in[7];
    const float* b       = (const float*)d_in[8];
    const float* Wout    = (const float*)d_in[9];
    const float* bout    = (const float*)d_in[10];
    float* out = (float*)d_out;

    const int n    = in_sizes[0] / 6;
    const int E_tp = in_sizes[1] / 2;
    const int E_it = in_sizes[2] / 2;
    const int B    = (n + 255) >> 8;   // 256-node buckets, <=1024

    float* h0      = (float*)d_ws;
    float* h1      = h0 + (size_t)n * 32;
    int*   deg_it  = (int*)(h1 + (size_t)n * 32);
    int*   row_it  = deg_it + n;
    float* inv_cnt = (float*)(row_it + n);
    int*   deg_tp  = (int*)(inv_cnt + n);       // zeroed
    int*   ctr     = deg_tp + n;                // zeroed
    int*   bcnt    = ctr + 1;                   // 1024, zeroed
    int*   bbase   = bcnt + 1024;               // 1025
    int*   bcursor = bbase + 1025;              // 1024
    int*   row_tp  = bcursor + 1024;
    int*   next_tp = row_tp + n;
    int*   col_it  = next_tp + n;
    int*   col_tp  = col_it + E_it;
    float* wcat    = (float*)(col_tp + E_tp);   // 13024 floats
    // d_out (102.4 MB): aggbuf = first n*64 floats (51.2 MB);
    // ebuf = next 25.6 MB — must survive all 4 agg32 layers; final_kernel
    // overwrites everything at the end.
    float* aggbuf = (float*)d_out;
    u64*   ebuf   = (u64*)((float*)d_out + (size_t)n * 64);

    hipMemsetAsync(deg_tp, 0, (size_t)(n + 1 + 1024) * sizeof(int), stream);

    prep_weights_kernel<<<51, 256, 0, stream>>>(W0_rel, W0_root, b0, W_rel, W_root, b, wcat);

    bucket_count_kernel<<<512, 256, 0, stream>>>(ei_it, E_it, B, bcnt);
    bucket_prefix_kernel<<<1, 256, 0, stream>>>(B, bcnt, bbase, bcursor);
    multisplit_kernel<<<(E_it + 2047) / 2048, 256, 0, stream>>>(ei_it, E_it, bcursor, ebuf);
    csr_it_kernel<<<B, 256, 0, stream>>>(n, ebuf, bbase, row_it, deg_it, inv_cnt, col_it);

    hist_tp_kernel<<<(E_tp + 255) / 256, 256, 0, stream>>>(ei_tp, E_tp, deg_tp);
    alloc_tp_kernel<<<(n + 255) / 256, 256, 0, stream>>>(n, deg_tp, row_tp, next_tp, ctr);
    fill_tp_kernel<<<(E_tp + 255) / 256, 256, 0, stream>>>(ei_tp, E_tp, next_tp, col_tp);

    const int gemm_blocks = (n + 255) / 256;

    agg6_kernel<<<(n + 31) / 32, 256, 0, stream>>>(n, x, row_it, deg_it, col_it,
                                                   row_tp, deg_tp, col_tp, inv_cnt, aggbuf);
    gemm_reg_kernel<6, false><<<gemm_blocks, 256, 0, stream>>>(
        n, aggbuf, x, wcat, wcat + 12864, h0);

    float* hin  = h0;
    float* hout = h1;
    for (int l = 0; l < 4; l++) {
        agg32_lds_kernel<<<B, 256, 0, stream>>>(n, hin, ebuf, bbase,
                                                row_tp, deg_tp, col_tp, inv_cnt, aggbuf);
        gemm_reg_kernel<32, true><<<gemm_blocks, 256, 0, stream>>>(
            n, aggbuf, hin, wcat + 576 + l * 3072, wcat + 12896 + l * 32, hout);
        float* t = hin; hin = hout; hout = t;
    }

    final_kernel<<<(n + 7) / 8, 256, 0, stream>>>(n, hin, Wout, bout, out);
}